// Round 5
// baseline (473.085 us; speedup 1.0000x reference)
//
#include <hip/hip_runtime.h>
#include <math.h>

#define LL 8192
#define DD 1024
#define DH 128

typedef unsigned long long u64;

// ---------------- fdlibm/glibc s_atanf.c bitwise port -----------------------
// Classic fdlibm float atan (glibc <=2.37 / musl). All f32 ops, NO fma
// contraction (pragma) — matches pre-FMA fdlibm arithmetic exactly.
__device__ __forceinline__ float fdlibm_atanf(float x) {
#pragma clang fp contract(off)
  const float atanhi0 = __uint_as_float(0x3eed6338u);  // atan(0.5)hi
  const float atanhi1 = __uint_as_float(0x3f490fdau);  // atan(1.0)hi
  const float atanhi2 = __uint_as_float(0x3f7b985eu);  // atan(1.5)hi
  const float atanhi3 = __uint_as_float(0x3fc90fdau);  // atan(inf)hi
  const float atanlo0 = __uint_as_float(0x31ac3769u);
  const float atanlo1 = __uint_as_float(0x33222168u);
  const float atanlo2 = __uint_as_float(0x33140fb4u);
  const float atanlo3 = __uint_as_float(0x33a22168u);
  const float aT0 = __uint_as_float(0x3eaaaaa9u);   //  3.3333328366e-01
  const float aT1 = __uint_as_float(0xbe4cca98u);   // -1.9999158382e-01
  const float aT2 = __uint_as_float(0x3e11f50du);   //  1.4253635705e-01
  const float aT3 = __uint_as_float(0xbdda1247u);   // -1.0648017377e-01
  const float aT4 = __uint_as_float(0x3d7cac25u);   //  6.1687607318e-02
  unsigned hx = __float_as_uint(x);
  unsigned ix = hx & 0x7fffffffu;
  int id;
  if (ix >= 0x4c800000u) {  // |x| >= 2^26
    if (ix > 0x7f800000u) return x + x;  // NaN
    float z = atanhi3 + atanlo3;
    return (hx >> 31) ? -z : z;
  }
  if (ix < 0x3ee00000u) {  // |x| < 0.4375
    if (ix < 0x39800000u) return x;  // |x| < 2^-12
    id = -1;
  } else {
    x = fabsf(x);
    if (ix < 0x3f980000u) {       // |x| < 1.1875
      if (ix < 0x3f300000u) {     // |x| < 0.6875
        id = 0; x = (2.0f * x - 1.0f) / (2.0f + x);
      } else {
        id = 1; x = (x - 1.0f) / (x + 1.0f);
      }
    } else {
      if (ix < 0x401c0000u) {     // |x| < 2.4375
        id = 2; x = (x - 1.5f) / (1.0f + 1.5f * x);
      } else {
        id = 3; x = -1.0f / x;
      }
    }
  }
  float z = x * x;
  float w = z * z;
  float s1 = z * (aT0 + w * (aT2 + w * aT4));
  float s2 = w * (aT1 + w * aT3);
  if (id < 0) return x - x * (s1 + s2);
  float r;
  if (id == 0)      r = atanhi0 - ((x * (s1 + s2) - atanlo0) - x);
  else if (id == 1) r = atanhi1 - ((x * (s1 + s2) - atanlo1) - x);
  else if (id == 2) r = atanhi2 - ((x * (s1 + s2) - atanlo2) - x);
  else              r = atanhi3 - ((x * (s1 + s2) - atanlo3) - x);
  return (hx >> 31) ? -r : r;
}

// ---------------- Kernel 1: f32-faithful hash keys --------------------------
// One thread per (row m, head h). proj = sequential f32 FMA chain over
// d=0..127 ascending (matches numpy einsum's contracted generic loop);
// f32 bias add, f32 eps add, IEEE f32 div, fdlibm atanf. Sort key =
// order-mapped f32 angle bits, index packed below (stable tie-break).
__global__ __launch_bounds__(256) void k_keys(const float* __restrict__ x,
                                              const float* __restrict__ hw,
                                              const float* __restrict__ hb,
                                              u64* __restrict__ ks) {
  __shared__ float2 wL[128][8];    // wL[d][h] = hash_w[h,d,0..1], 8KB
  __shared__ float projL[32][16];  // 2KB
  const int tid = threadIdx.x;
  const float2* hw2 = (const float2*)hw;
  for (int i = tid; i < 1024; i += 256) {
    int hh = i >> 7, dd = i & 127;
    wL[dd][hh] = hw2[i];
  }
  __syncthreads();
  const int r = tid >> 3;  // local row 0..31
  const int h = tid & 7;
  const int m = blockIdx.x * 32 + r;
  const float4* xp = (const float4*)(x + (size_t)m * DD + h * DH);
  float a0 = 0.f, a1 = 0.f;
#pragma unroll
  for (int q = 0; q < 32; ++q) {
    float4 v = xp[q];
    float2 w0 = wL[q * 4 + 0][h];
    float2 w1 = wL[q * 4 + 1][h];
    float2 w2 = wL[q * 4 + 2][h];
    float2 w3 = wL[q * 4 + 3][h];
    a0 = fmaf(v.x, w0.x, a0); a1 = fmaf(v.x, w0.y, a1);
    a0 = fmaf(v.y, w1.x, a0); a1 = fmaf(v.y, w1.y, a1);
    a0 = fmaf(v.z, w2.x, a0); a1 = fmaf(v.z, w2.y, a1);
    a0 = fmaf(v.w, w3.x, a0); a1 = fmaf(v.w, w3.y, a1);
  }
  projL[r][h * 2 + 0] = a0;
  projL[r][h * 2 + 1] = a1;
  __syncthreads();
  const int j = h;  // slot j handled by thread (r, h=j)
  float px = projL[r][j] + hb[j];
  float py = projL[r][8 + j] + hb[8 + j];
  float den = py + 1e-4f;
  float ratio = px / den;
  float angle = fdlibm_atanf(ratio);
  unsigned am = __float_as_uint(angle);
  am = (am & 0x80000000u) ? ~am : (am | 0x80000000u);
  const int b = m >> 13, l = m & (LL - 1);
  ks[((size_t)b * 8 + j) * LL + l] = ((u64)am << 13) | (u64)l;
}

// ---------------- Kernel 2: bitonic argsort per (b,slot) --------------------
__global__ __launch_bounds__(1024) void k_sort(const u64* __restrict__ ks,
                                               int* __restrict__ perm) {
  __shared__ u64 sk[LL];  // 64 KB
  const int tid = threadIdx.x;
  const u64* src = ks + (size_t)blockIdx.x * LL;
#pragma unroll
  for (int i = 0; i < LL / 1024; ++i) sk[tid + i * 1024] = src[tid + i * 1024];
  __syncthreads();
  for (int size = 2; size <= LL; size <<= 1) {
    for (int stride = size >> 1; stride > 0; stride >>= 1) {
      for (int pp = tid; pp < LL / 2; pp += 1024) {
        int i = 2 * pp - (pp & (stride - 1));
        int j = i + stride;
        u64 a = sk[i], c = sk[j];
        bool up = ((i & size) == 0);
        if ((a > c) == up) { sk[i] = c; sk[j] = a; }
      }
      __syncthreads();
    }
  }
  int* dst = perm + (size_t)blockIdx.x * LL;
#pragma unroll
  for (int i = 0; i < LL / 1024; ++i) {
    int r = tid + i * 1024;
    dst[r] = (int)(sk[r] & (u64)(LL - 1));
  }
}

// ---------------- Kernel 3: weight transpose Wt[h][k=t*128+i][o] ------------
__global__ __launch_bounds__(256) void k_wt(const float* __restrict__ cw,
                                            float* __restrict__ wt) {
  int g = blockIdx.x * 256 + threadIdx.x;  // ((h*384 + k)*128 + o)
  if (g >= 8 * 384 * 128) return;
  int o = g & 127;
  int hk = g >> 7;
  int k = hk % 384;
  int h = hk / 384;
  int i = k & 127, t = k >> 7;
  wt[g] = cw[((size_t)(h * 128 + o)) * 384 + i * 3 + t];
}

// ---------------- Kernel 4: fused gather + grouped conv + scatter -----------
// Block = (b,h,64-rank tile). K = 384 (3 taps x 128 ch) split into 12 chunks
// of 32 k-values; each chunk's weights (32k x 128o = 16KB) staged in WsL.
__global__ __launch_bounds__(256) void k_conv(const float* __restrict__ x,
                                              const float* __restrict__ wt,
                                              const float* __restrict__ bias,
                                              const int* __restrict__ perm,
                                              float* __restrict__ out) {
  __shared__ float XsL[66 * 128];  // 33792 B
  __shared__ float WsL[32 * 128];  // 16384 B
  const int tid = threadIdx.x;
  const int bid = blockIdx.x;      // 4*8*128 = 4096 blocks
  const int tile = bid & 127;
  const int h = (bid >> 7) & 7;
  const int b = bid >> 10;
  const int r0 = tile * 64;
  const int* pbh = perm + ((size_t)b * 8 + h) * LL;
  float4* XsL4 = (float4*)XsL;
  // gather rows r0-1 .. r0+64 (wrap), each 128 f32 contiguous in x
  for (int j = (tid >> 5); j < 66; j += 8) {
    int rank = (r0 + j - 1 + LL) & (LL - 1);
    int src = pbh[rank];
    const float4* sp = (const float4*)(x + ((size_t)(b * LL + src)) * DD + h * DH);
    XsL4[j * 32 + (tid & 31)] = sp[tid & 31];
  }
  const int ot = tid & 31;   // 4 output channels: h*128 + ot*4 ..
  const int rt = tid >> 5;   // 8 ranks: r0 + rt*8 ..
  const float4* wp4 = (const float4*)(wt + (size_t)h * 384 * 128);
  float4* WsL4 = (float4*)WsL;
  float acc[8][4];
#pragma unroll
  for (int s = 0; s < 8; ++s)
#pragma unroll
    for (int c = 0; c < 4; ++c) acc[s][c] = 0.f;
  for (int kc = 0; kc < 12; ++kc) {   // 12 chunks x 32 k-values = K=384
    __syncthreads();  // covers gather (kc=0) and WsL reuse (kc>0)
    for (int q = tid; q < 1024; q += 256) WsL4[q] = wp4[kc * 1024 + q];
    __syncthreads();
#pragma unroll
    for (int k4i = 0; k4i < 8; ++k4i) {
      float4 w0 = WsL4[(k4i * 4 + 0) * 32 + ot];
      float4 w1 = WsL4[(k4i * 4 + 1) * 32 + ot];
      float4 w2 = WsL4[(k4i * 4 + 2) * 32 + ot];
      float4 w3 = WsL4[(k4i * 4 + 3) * 32 + ot];
      const int kg = kc * 8 + k4i;
#pragma unroll
      for (int s = 0; s < 8; ++s) {
        float4 xv = XsL4[(rt * 8 + s) * 32 + kg];
        acc[s][0] = fmaf(xv.x, w0.x, acc[s][0]);
        acc[s][0] = fmaf(xv.y, w1.x, acc[s][0]);
        acc[s][0] = fmaf(xv.z, w2.x, acc[s][0]);
        acc[s][0] = fmaf(xv.w, w3.x, acc[s][0]);
        acc[s][1] = fmaf(xv.x, w0.y, acc[s][1]);
        acc[s][1] = fmaf(xv.y, w1.y, acc[s][1]);
        acc[s][1] = fmaf(xv.z, w2.y, acc[s][1]);
        acc[s][1] = fmaf(xv.w, w3.y, acc[s][1]);
        acc[s][2] = fmaf(xv.x, w0.z, acc[s][2]);
        acc[s][2] = fmaf(xv.y, w1.z, acc[s][2]);
        acc[s][2] = fmaf(xv.z, w2.z, acc[s][2]);
        acc[s][2] = fmaf(xv.w, w3.z, acc[s][2]);
        acc[s][3] = fmaf(xv.x, w0.w, acc[s][3]);
        acc[s][3] = fmaf(xv.y, w1.w, acc[s][3]);
        acc[s][3] = fmaf(xv.z, w2.w, acc[s][3]);
        acc[s][3] = fmaf(xv.w, w3.w, acc[s][3]);
      }
    }
  }
  float4 bv = ((const float4*)(bias + h * DH))[ot];
#pragma unroll
  for (int s = 0; s < 8; ++s) {
    int rank = r0 + rt * 8 + s;
    int dst = pbh[rank];
    float4* op = (float4*)(out + ((size_t)(b * LL + dst)) * DD + h * DH) + ot;
    float4 v;
    v.x = acc[s][0] + bv.x;
    v.y = acc[s][1] + bv.y;
    v.z = acc[s][2] + bv.z;
    v.w = acc[s][3] + bv.w;
    *op = v;
  }
}

extern "C" void kernel_launch(void* const* d_in, const int* in_sizes, int n_in,
                              void* d_out, int out_size, void* d_ws, size_t ws_size,
                              hipStream_t stream) {
  const float* x  = (const float*)d_in[0];
  const float* hw = (const float*)d_in[1];
  const float* hb = (const float*)d_in[2];
  const float* cw = (const float*)d_in[3];
  const float* cb = (const float*)d_in[4];
  float* out = (float*)d_out;
  // workspace: ks 2MB | perm 1MB | Wt 1.5MB  (4.5MB total)
  u64* ks   = (u64*)d_ws;
  int* perm = (int*)((char*)d_ws + (2u << 20));
  float* wt = (float*)((char*)d_ws + (3u << 20));

  k_keys<<<1024, 256, 0, stream>>>(x, hw, hb, ks);
  k_wt<<<1536, 256, 0, stream>>>(cw, wt);
  k_sort<<<32, 1024, 0, stream>>>(ks, perm);
  k_conv<<<4096, 256, 0, stream>>>(x, wt, cb, perm, out);
}

// Round 6
// 167.071 us; speedup vs baseline: 2.8316x; 2.8316x over previous
//
#include <hip/hip_runtime.h>
#include <math.h>

#define LL 8192
#define DD 1024
#define DH 128

typedef unsigned long long u64;
typedef __attribute__((ext_vector_type(8))) short bf16x8;
typedef __attribute__((ext_vector_type(4))) float f32x4;

__device__ __forceinline__ unsigned short f2bf(float f) {
  unsigned u = __float_as_uint(f);
  u = (u + 0x7fffu + ((u >> 16) & 1u)) >> 16;  // RNE to bf16
  return (unsigned short)u;
}

// ---------------- fdlibm/glibc s_atanf.c bitwise port -----------------------
__device__ __forceinline__ float fdlibm_atanf(float x) {
#pragma clang fp contract(off)
  const float atanhi0 = __uint_as_float(0x3eed6338u);
  const float atanhi1 = __uint_as_float(0x3f490fdau);
  const float atanhi2 = __uint_as_float(0x3f7b985eu);
  const float atanhi3 = __uint_as_float(0x3fc90fdau);
  const float atanlo0 = __uint_as_float(0x31ac3769u);
  const float atanlo1 = __uint_as_float(0x33222168u);
  const float atanlo2 = __uint_as_float(0x33140fb4u);
  const float atanlo3 = __uint_as_float(0x33a22168u);
  const float aT0 = __uint_as_float(0x3eaaaaa9u);
  const float aT1 = __uint_as_float(0xbe4cca98u);
  const float aT2 = __uint_as_float(0x3e11f50du);
  const float aT3 = __uint_as_float(0xbdda1247u);
  const float aT4 = __uint_as_float(0x3d7cac25u);
  unsigned hx = __float_as_uint(x);
  unsigned ix = hx & 0x7fffffffu;
  int id;
  if (ix >= 0x4c800000u) {
    if (ix > 0x7f800000u) return x + x;
    float z = atanhi3 + atanlo3;
    return (hx >> 31) ? -z : z;
  }
  if (ix < 0x3ee00000u) {
    if (ix < 0x39800000u) return x;
    id = -1;
  } else {
    x = fabsf(x);
    if (ix < 0x3f980000u) {
      if (ix < 0x3f300000u) { id = 0; x = (2.0f * x - 1.0f) / (2.0f + x); }
      else                  { id = 1; x = (x - 1.0f) / (x + 1.0f); }
    } else {
      if (ix < 0x401c0000u) { id = 2; x = (x - 1.5f) / (1.0f + 1.5f * x); }
      else                  { id = 3; x = -1.0f / x; }
    }
  }
  float z = x * x;
  float w = z * z;
  float s1 = z * (aT0 + w * (aT2 + w * aT4));
  float s2 = w * (aT1 + w * aT3);
  if (id < 0) return x - x * (s1 + s2);
  float r;
  if (id == 0)      r = atanhi0 - ((x * (s1 + s2) - atanlo0) - x);
  else if (id == 1) r = atanhi1 - ((x * (s1 + s2) - atanlo1) - x);
  else if (id == 2) r = atanhi2 - ((x * (s1 + s2) - atanlo2) - x);
  else              r = atanhi3 - ((x * (s1 + s2) - atanlo3) - x);
  return (hx >> 31) ? -r : r;
}

// ---------------- Kernel 1: f32-faithful hash keys (FROZEN — passes) --------
__global__ __launch_bounds__(256) void k_keys(const float* __restrict__ x,
                                              const float* __restrict__ hw,
                                              const float* __restrict__ hb,
                                              u64* __restrict__ ks) {
  __shared__ float2 wL[128][8];
  __shared__ float projL[32][16];
  const int tid = threadIdx.x;
  const float2* hw2 = (const float2*)hw;
  for (int i = tid; i < 1024; i += 256) {
    int hh = i >> 7, dd = i & 127;
    wL[dd][hh] = hw2[i];
  }
  __syncthreads();
  const int r = tid >> 3;
  const int h = tid & 7;
  const int m = blockIdx.x * 32 + r;
  const float4* xp = (const float4*)(x + (size_t)m * DD + h * DH);
  float a0 = 0.f, a1 = 0.f;
#pragma unroll
  for (int q = 0; q < 32; ++q) {
    float4 v = xp[q];
    float2 w0 = wL[q * 4 + 0][h];
    float2 w1 = wL[q * 4 + 1][h];
    float2 w2 = wL[q * 4 + 2][h];
    float2 w3 = wL[q * 4 + 3][h];
    a0 = fmaf(v.x, w0.x, a0); a1 = fmaf(v.x, w0.y, a1);
    a0 = fmaf(v.y, w1.x, a0); a1 = fmaf(v.y, w1.y, a1);
    a0 = fmaf(v.z, w2.x, a0); a1 = fmaf(v.z, w2.y, a1);
    a0 = fmaf(v.w, w3.x, a0); a1 = fmaf(v.w, w3.y, a1);
  }
  projL[r][h * 2 + 0] = a0;
  projL[r][h * 2 + 1] = a1;
  __syncthreads();
  const int j = h;
  float px = projL[r][j] + hb[j];
  float py = projL[r][8 + j] + hb[8 + j];
  float den = py + 1e-4f;
  float ratio = px / den;
  float angle = fdlibm_atanf(ratio);
  unsigned am = __float_as_uint(angle);
  am = (am & 0x80000000u) ? ~am : (am | 0x80000000u);
  const int b = m >> 13, l = m & (LL - 1);
  ks[((size_t)b * 8 + j) * LL + l] = ((u64)am << 13) | (u64)l;
}

// ---------------- Kernel 2: bitonic argsort per (b,slot) (FROZEN) -----------
__global__ __launch_bounds__(1024) void k_sort(const u64* __restrict__ ks,
                                               int* __restrict__ perm) {
  __shared__ u64 sk[LL];
  const int tid = threadIdx.x;
  const u64* src = ks + (size_t)blockIdx.x * LL;
#pragma unroll
  for (int i = 0; i < LL / 1024; ++i) sk[tid + i * 1024] = src[tid + i * 1024];
  __syncthreads();
  for (int size = 2; size <= LL; size <<= 1) {
    for (int stride = size >> 1; stride > 0; stride >>= 1) {
      for (int pp = tid; pp < LL / 2; pp += 1024) {
        int i = 2 * pp - (pp & (stride - 1));
        int j = i + stride;
        u64 a = sk[i], c = sk[j];
        bool up = ((i & size) == 0);
        if ((a > c) == up) { sk[i] = c; sk[j] = a; }
      }
      __syncthreads();
    }
  }
  int* dst = perm + (size_t)blockIdx.x * LL;
#pragma unroll
  for (int i = 0; i < LL / 1024; ++i) {
    int r = tid + i * 1024;
    dst[r] = (int)(sk[r] & (u64)(LL - 1));
  }
}

// ---------------- Kernel 3: W pack into MFMA B-fragment order, bf16 ---------
// Wb[h][kk(12)][n(8)][lane(64)][j(8)]: k = kk*32 + (lane>>4)*8 + j,
// o = n*16 + (lane&15); source cw[(h*128+o)*384 + (k&127)*3 + (k>>7)].
// Same lane->k map as the A-side LDS read, so any k-permutation cancels.
__global__ __launch_bounds__(256) void k_wt(const float* __restrict__ cw,
                                            unsigned short* __restrict__ wb) {
  int g = blockIdx.x * 256 + threadIdx.x;
  if (g >= 8 * 12 * 8 * 64 * 8) return;
  int h = g / 49152;
  int rem = g % 49152;
  int kk = rem >> 12;
  int rem2 = rem & 4095;
  int n = rem2 >> 9;
  int rem3 = rem2 & 511;
  int l = rem3 >> 3;
  int j = rem3 & 7;
  int k = kk * 32 + ((l >> 4) * 8) + j;
  int o = n * 16 + (l & 15);
  int t = k >> 7, i = k & 127;
  wb[g] = f2bf(cw[((size_t)(h * 128 + o)) * 384 + i * 3 + t]);
}

// ---------------- Kernel 4: MFMA gather-conv-scatter ------------------------
// Block = (b,h,64-rank tile), 4 waves; wave w owns local rows w*16..+15 x 128
// outs = 8 mfma_f32_16x16x32_bf16 acc tiles. X staged bf16 [66][136] (row pad
// 272B -> 2-way/free LDS); W chunk (32k x 128o, fragment-ordered) 8KB/step.
__global__ __launch_bounds__(256) void k_conv(const float* __restrict__ x,
                                              const unsigned short* __restrict__ wb,
                                              const float* __restrict__ bias,
                                              const int* __restrict__ perm,
                                              float* __restrict__ out) {
  __shared__ short Xs[66 * 136];   // 17952 B
  __shared__ short Ws[8 * 64 * 8]; // 8192 B
  __shared__ int Ps[64];
  const int tid = threadIdx.x;
  const int bid = blockIdx.x;      // 4*8*128
  const int tile = bid & 127;
  const int h = (bid >> 7) & 7;
  const int b = bid >> 10;
  const int r0 = tile * 64;
  const int* pbh = perm + ((size_t)b * 8 + h) * LL;
  if (tid < 64) Ps[tid] = pbh[r0 + tid];
  // stage X rows r0-1..r0+64 (wrap) as bf16
  {
    const int ln = tid & 31;
    for (int j = (tid >> 5); j < 66; j += 8) {
      int rank = (r0 + j - 1 + LL) & (LL - 1);
      int src = pbh[rank];
      float4 v = ((const float4*)(x + ((size_t)(b * LL + src)) * DD + h * DH))[ln];
      uint2 pk;
      pk.x = (unsigned)f2bf(v.x) | ((unsigned)f2bf(v.y) << 16);
      pk.y = (unsigned)f2bf(v.z) | ((unsigned)f2bf(v.w) << 16);
      *(uint2*)(Xs + j * 136 + ln * 4) = pk;
    }
  }
  const int w = tid >> 6;
  const int l = tid & 63;
  const int arow = w * 16 + (l & 15);      // A-operand local row
  const int acol = (l >> 4) * 8;           // A-operand k sub-offset (bf16)
  f32x4 acc[8];
#pragma unroll
  for (int n = 0; n < 8; ++n) acc[n] = (f32x4){0.f, 0.f, 0.f, 0.f};
  const uint4* wsrc = (const uint4*)(wb + (size_t)h * 49152);
  uint4* Ws16 = (uint4*)Ws;
  for (int kk = 0; kk < 12; ++kk) {
    __syncthreads();  // Ws reuse (and X/Ps visibility at kk=0)
    Ws16[tid] = wsrc[kk * 512 + tid];
    Ws16[tid + 256] = wsrc[kk * 512 + tid + 256];
    __syncthreads();
    bf16x8 af = *(const bf16x8*)(Xs + (arow + (kk >> 2)) * 136 + (kk & 3) * 32 + acol);
#pragma unroll
    for (int n = 0; n < 8; ++n) {
      bf16x8 bf_ = *(const bf16x8*)(Ws + (n * 64 + l) * 8);
      acc[n] = __builtin_amdgcn_mfma_f32_16x16x32_bf16(af, bf_, acc[n], 0, 0, 0);
    }
  }
  // epilogue: C tile layout col=lane&15, row=(lane>>4)*4+reg (m89-verified)
  int dsts[4];
#pragma unroll
  for (int reg = 0; reg < 4; ++reg) dsts[reg] = Ps[w * 16 + (l >> 4) * 4 + reg];
#pragma unroll
  for (int n = 0; n < 8; ++n) {
    int o = h * DH + n * 16 + (l & 15);
    float bv = bias[o];
#pragma unroll
    for (int reg = 0; reg < 4; ++reg) {
      out[((size_t)(b * LL + dsts[reg])) * DD + o] = acc[n][reg] + bv;
    }
  }
}

extern "C" void kernel_launch(void* const* d_in, const int* in_sizes, int n_in,
                              void* d_out, int out_size, void* d_ws, size_t ws_size,
                              hipStream_t stream) {
  const float* x  = (const float*)d_in[0];
  const float* hw = (const float*)d_in[1];
  const float* hb = (const float*)d_in[2];
  const float* cw = (const float*)d_in[3];
  const float* cb = (const float*)d_in[4];
  float* out = (float*)d_out;
  // workspace: ks 2MB | perm 1MB | Wb(bf16 fragment-packed) 0.77MB
  u64* ks   = (u64*)d_ws;
  int* perm = (int*)((char*)d_ws + (2u << 20));
  unsigned short* wbp = (unsigned short*)((char*)d_ws + (3u << 20));

  k_keys<<<1024, 256, 0, stream>>>(x, hw, hb, ks);
  k_wt<<<1536, 256, 0, stream>>>(cw, wbp);
  k_sort<<<32, 1024, 0, stream>>>(ks, perm);
  k_conv<<<4096, 256, 0, stream>>>(x, wbp, cb, perm, out);
}

// Round 7
// 125.568 us; speedup vs baseline: 3.7676x; 1.3305x over previous
//
#include <hip/hip_runtime.h>
#include <math.h>

#define LL 8192
#define DD 1024
#define DH 128

typedef unsigned long long u64;
typedef __attribute__((ext_vector_type(8))) short bf16x8;
typedef __attribute__((ext_vector_type(4))) float f32x4;

__device__ __forceinline__ unsigned short f2bf(float f) {
  unsigned u = __float_as_uint(f);
  u = (u + 0x7fffu + ((u >> 16) & 1u)) >> 16;  // RNE to bf16
  return (unsigned short)u;
}

// ---------------- fdlibm/glibc s_atanf.c bitwise port -----------------------
__device__ __forceinline__ float fdlibm_atanf(float x) {
#pragma clang fp contract(off)
  const float atanhi0 = __uint_as_float(0x3eed6338u);
  const float atanhi1 = __uint_as_float(0x3f490fdau);
  const float atanhi2 = __uint_as_float(0x3f7b985eu);
  const float atanhi3 = __uint_as_float(0x3fc90fdau);
  const float atanlo0 = __uint_as_float(0x31ac3769u);
  const float atanlo1 = __uint_as_float(0x33222168u);
  const float atanlo2 = __uint_as_float(0x33140fb4u);
  const float atanlo3 = __uint_as_float(0x33a22168u);
  const float aT0 = __uint_as_float(0x3eaaaaa9u);
  const float aT1 = __uint_as_float(0xbe4cca98u);
  const float aT2 = __uint_as_float(0x3e11f50du);
  const float aT3 = __uint_as_float(0xbdda1247u);
  const float aT4 = __uint_as_float(0x3d7cac25u);
  unsigned hx = __float_as_uint(x);
  unsigned ix = hx & 0x7fffffffu;
  int id;
  if (ix >= 0x4c800000u) {
    if (ix > 0x7f800000u) return x + x;
    float z = atanhi3 + atanlo3;
    return (hx >> 31) ? -z : z;
  }
  if (ix < 0x3ee00000u) {
    if (ix < 0x39800000u) return x;
    id = -1;
  } else {
    x = fabsf(x);
    if (ix < 0x3f980000u) {
      if (ix < 0x3f300000u) { id = 0; x = (2.0f * x - 1.0f) / (2.0f + x); }
      else                  { id = 1; x = (x - 1.0f) / (x + 1.0f); }
    } else {
      if (ix < 0x401c0000u) { id = 2; x = (x - 1.5f) / (1.0f + 1.5f * x); }
      else                  { id = 3; x = -1.0f / x; }
    }
  }
  float z = x * x;
  float w = z * z;
  float s1 = z * (aT0 + w * (aT2 + w * aT4));
  float s2 = w * (aT1 + w * aT3);
  if (id < 0) return x - x * (s1 + s2);
  float r;
  if (id == 0)      r = atanhi0 - ((x * (s1 + s2) - atanlo0) - x);
  else if (id == 1) r = atanhi1 - ((x * (s1 + s2) - atanlo1) - x);
  else if (id == 2) r = atanhi2 - ((x * (s1 + s2) - atanlo2) - x);
  else              r = atanhi3 - ((x * (s1 + s2) - atanlo3) - x);
  return (hx >> 31) ? -r : r;
}

// ---------------- Kernel 1: f32-faithful hash keys (FROZEN — passes) --------
__global__ __launch_bounds__(256) void k_keys(const float* __restrict__ x,
                                              const float* __restrict__ hw,
                                              const float* __restrict__ hb,
                                              u64* __restrict__ ks) {
  __shared__ float2 wL[128][8];
  __shared__ float projL[32][16];
  const int tid = threadIdx.x;
  const float2* hw2 = (const float2*)hw;
  for (int i = tid; i < 1024; i += 256) {
    int hh = i >> 7, dd = i & 127;
    wL[dd][hh] = hw2[i];
  }
  __syncthreads();
  const int r = tid >> 3;
  const int h = tid & 7;
  const int m = blockIdx.x * 32 + r;
  const float4* xp = (const float4*)(x + (size_t)m * DD + h * DH);
  float a0 = 0.f, a1 = 0.f;
#pragma unroll
  for (int q = 0; q < 32; ++q) {
    float4 v = xp[q];
    float2 w0 = wL[q * 4 + 0][h];
    float2 w1 = wL[q * 4 + 1][h];
    float2 w2 = wL[q * 4 + 2][h];
    float2 w3 = wL[q * 4 + 3][h];
    a0 = fmaf(v.x, w0.x, a0); a1 = fmaf(v.x, w0.y, a1);
    a0 = fmaf(v.y, w1.x, a0); a1 = fmaf(v.y, w1.y, a1);
    a0 = fmaf(v.z, w2.x, a0); a1 = fmaf(v.z, w2.y, a1);
    a0 = fmaf(v.w, w3.x, a0); a1 = fmaf(v.w, w3.y, a1);
  }
  projL[r][h * 2 + 0] = a0;
  projL[r][h * 2 + 1] = a1;
  __syncthreads();
  const int j = h;
  float px = projL[r][j] + hb[j];
  float py = projL[r][8 + j] + hb[8 + j];
  float den = py + 1e-4f;
  float ratio = px / den;
  float angle = fdlibm_atanf(ratio);
  unsigned am = __float_as_uint(angle);
  am = (am & 0x80000000u) ? ~am : (am | 0x80000000u);
  const int b = m >> 13, l = m & (LL - 1);
  ks[((size_t)b * 8 + j) * LL + l] = ((u64)am << 13) | (u64)l;
}

// ---------------- Sort: bitonic network, stride-decomposed ------------------
// Identical network to the verified monolithic bitonic; strides <=1024 are
// 2048-chunk-local (pair span 2*stride, aligned), strides >=2048 run as
// global disjoint-pair kernels. Direction bit from in-segment index.
__global__ __launch_bounds__(1024) void k_sort_loc(u64* __restrict__ ks) {
  __shared__ u64 sk[2048];  // 16 KB
  const int blk = blockIdx.x;             // 128 = 32 segs * 4 chunks
  const int seg = blk >> 2, c = blk & 3;
  u64* base = ks + (size_t)seg * LL + c * 2048;
  const int tid = threadIdx.x;
  sk[tid] = base[tid];
  sk[tid + 1024] = base[tid + 1024];
  __syncthreads();
  const int cb = c * 2048;
  for (int size = 2; size <= 2048; size <<= 1) {
    for (int stride = size >> 1; stride > 0; stride >>= 1) {
      int i = 2 * tid - (tid & (stride - 1));
      int j = i + stride;
      bool up = (((cb + i) & size) == 0);
      u64 a = sk[i], d = sk[j];
      if ((a > d) == up) { sk[i] = d; sk[j] = a; }
      __syncthreads();
    }
  }
  base[tid] = sk[tid];
  base[tid + 1024] = sk[tid + 1024];
}

__global__ __launch_bounds__(256) void k_sort_glob(u64* __restrict__ ks,
                                                   int size, int stride) {
  int t = blockIdx.x * 256 + threadIdx.x;  // 131072 = 32 segs * 4096 pairs
  int seg = t >> 12, p = t & 4095;
  int i = 2 * p - (p & (stride - 1));
  int j = i + stride;
  u64* base = ks + (size_t)seg * LL;
  bool up = ((i & size) == 0);
  u64 a = base[i], d = base[j];
  if ((a > d) == up) { base[i] = d; base[j] = a; }
}

__global__ __launch_bounds__(1024) void k_sort_tail(u64* __restrict__ ks,
                                                    int size,
                                                    int* __restrict__ perm) {
  __shared__ u64 sk[2048];
  const int blk = blockIdx.x;
  const int seg = blk >> 2, c = blk & 3;
  u64* base = ks + (size_t)seg * LL + c * 2048;
  const int tid = threadIdx.x;
  sk[tid] = base[tid];
  sk[tid + 1024] = base[tid + 1024];
  __syncthreads();
  const int cb = c * 2048;
  for (int stride = 1024; stride > 0; stride >>= 1) {
    int i = 2 * tid - (tid & (stride - 1));
    int j = i + stride;
    bool up = (((cb + i) & size) == 0);
    u64 a = sk[i], d = sk[j];
    if ((a > d) == up) { sk[i] = d; sk[j] = a; }
    __syncthreads();
  }
  if (perm) {
    int* dst = perm + (size_t)seg * LL + c * 2048;
    dst[tid] = (int)(sk[tid] & (u64)(LL - 1));
    dst[tid + 1024] = (int)(sk[tid + 1024] & (u64)(LL - 1));
  } else {
    base[tid] = sk[tid];
    base[tid + 1024] = sk[tid + 1024];
  }
}

// ---------------- Kernel 3: W pack into MFMA B-fragment order (FROZEN) ------
__global__ __launch_bounds__(256) void k_wt(const float* __restrict__ cw,
                                            unsigned short* __restrict__ wb) {
  int g = blockIdx.x * 256 + threadIdx.x;
  if (g >= 8 * 12 * 8 * 64 * 8) return;
  int h = g / 49152;
  int rem = g % 49152;
  int kk = rem >> 12;
  int rem2 = rem & 4095;
  int n = rem2 >> 9;
  int rem3 = rem2 & 511;
  int l = rem3 >> 3;
  int j = rem3 & 7;
  int k = kk * 32 + ((l >> 4) * 8) + j;
  int o = n * 16 + (l & 15);
  int t = k >> 7, i = k & 127;
  wb[g] = f2bf(cw[((size_t)(h * 128 + o)) * 384 + i * 3 + t]);
}

// ---------------- Kernel 4: MFMA gather-conv-scatter (FROZEN) ---------------
__global__ __launch_bounds__(256) void k_conv(const float* __restrict__ x,
                                              const unsigned short* __restrict__ wb,
                                              const float* __restrict__ bias,
                                              const int* __restrict__ perm,
                                              float* __restrict__ out) {
  __shared__ short Xs[66 * 136];   // 17952 B
  __shared__ short Ws[8 * 64 * 8]; // 8192 B
  __shared__ int Ps[64];
  const int tid = threadIdx.x;
  const int bid = blockIdx.x;      // 4*8*128
  const int tile = bid & 127;
  const int h = (bid >> 7) & 7;
  const int b = bid >> 10;
  const int r0 = tile * 64;
  const int* pbh = perm + ((size_t)b * 8 + h) * LL;
  if (tid < 64) Ps[tid] = pbh[r0 + tid];
  {
    const int ln = tid & 31;
    for (int j = (tid >> 5); j < 66; j += 8) {
      int rank = (r0 + j - 1 + LL) & (LL - 1);
      int src = pbh[rank];
      float4 v = ((const float4*)(x + ((size_t)(b * LL + src)) * DD + h * DH))[ln];
      uint2 pk;
      pk.x = (unsigned)f2bf(v.x) | ((unsigned)f2bf(v.y) << 16);
      pk.y = (unsigned)f2bf(v.z) | ((unsigned)f2bf(v.w) << 16);
      *(uint2*)(Xs + j * 136 + ln * 4) = pk;
    }
  }
  const int w = tid >> 6;
  const int l = tid & 63;
  const int arow = w * 16 + (l & 15);
  const int acol = (l >> 4) * 8;
  f32x4 acc[8];
#pragma unroll
  for (int n = 0; n < 8; ++n) acc[n] = (f32x4){0.f, 0.f, 0.f, 0.f};
  const uint4* wsrc = (const uint4*)(wb + (size_t)h * 49152);
  uint4* Ws16 = (uint4*)Ws;
  for (int kk = 0; kk < 12; ++kk) {
    __syncthreads();
    Ws16[tid] = wsrc[kk * 512 + tid];
    Ws16[tid + 256] = wsrc[kk * 512 + tid + 256];
    __syncthreads();
    bf16x8 af = *(const bf16x8*)(Xs + (arow + (kk >> 2)) * 136 + (kk & 3) * 32 + acol);
#pragma unroll
    for (int n = 0; n < 8; ++n) {
      bf16x8 bf_ = *(const bf16x8*)(Ws + (n * 64 + l) * 8);
      acc[n] = __builtin_amdgcn_mfma_f32_16x16x32_bf16(af, bf_, acc[n], 0, 0, 0);
    }
  }
  int dsts[4];
#pragma unroll
  for (int reg = 0; reg < 4; ++reg) dsts[reg] = Ps[w * 16 + (l >> 4) * 4 + reg];
#pragma unroll
  for (int n = 0; n < 8; ++n) {
    int o = h * DH + n * 16 + (l & 15);
    float bv = bias[o];
#pragma unroll
    for (int reg = 0; reg < 4; ++reg) {
      out[((size_t)(b * LL + dsts[reg])) * DD + o] = acc[n][reg] + bv;
    }
  }
}

extern "C" void kernel_launch(void* const* d_in, const int* in_sizes, int n_in,
                              void* d_out, int out_size, void* d_ws, size_t ws_size,
                              hipStream_t stream) {
  const float* x  = (const float*)d_in[0];
  const float* hw = (const float*)d_in[1];
  const float* hb = (const float*)d_in[2];
  const float* cw = (const float*)d_in[3];
  const float* cb = (const float*)d_in[4];
  float* out = (float*)d_out;
  // workspace: ks 2MB | perm 1MB | Wb(bf16 fragment-packed) 0.77MB
  u64* ks   = (u64*)d_ws;
  int* perm = (int*)((char*)d_ws + (2u << 20));
  unsigned short* wbp = (unsigned short*)((char*)d_ws + (3u << 20));

  k_keys<<<1024, 256, 0, stream>>>(x, hw, hb, ks);
  k_wt<<<1536, 256, 0, stream>>>(cw, wbp);
  // bitonic network, stride-decomposed (identical compare sequence):
  k_sort_loc<<<128, 1024, 0, stream>>>(ks);                   // sizes 2..2048
  k_sort_glob<<<512, 256, 0, stream>>>(ks, 4096, 2048);       // size 4096, stride 2048
  k_sort_tail<<<128, 1024, 0, stream>>>(ks, 4096, nullptr);   // size 4096, strides 1024..1
  k_sort_glob<<<512, 256, 0, stream>>>(ks, 8192, 4096);       // size 8192, stride 4096
  k_sort_glob<<<512, 256, 0, stream>>>(ks, 8192, 2048);       // size 8192, stride 2048
  k_sort_tail<<<128, 1024, 0, stream>>>(ks, 8192, perm);      // size 8192, strides 1024..1 + perm
  k_conv<<<4096, 256, 0, stream>>>(x, wbp, cb, perm, out);
}